// Round 2
// baseline (220.486 us; speedup 1.0000x reference)
//
#include <hip/hip_runtime.h>

#define TSEQ 512
#define NB   128
#define CDIM 384
#define HD   64
#define QSCALE 0.051031036307982884f   // 384^-0.5, folded into Q at projection
#define MBIAS  8.0f                    // fixed softmax offset (exact: cancels in O=PV/l)

typedef _Float16 half8  __attribute__((ext_vector_type(8)));
typedef _Float16 half4  __attribute__((ext_vector_type(4)));
typedef float    floatx4 __attribute__((ext_vector_type(4)));

typedef __attribute__((address_space(3))) unsigned int lds_u32;
typedef const __attribute__((address_space(1))) unsigned int g_u32;

__device__ __forceinline__ void load_lds16(const void* g, void* l) {
    // async global->LDS DMA, 16B/lane; LDS dst = wave-uniform base + lane*16
    __builtin_amdgcn_global_load_lds((g_u32*)g, (lds_u32*)l, 16, 0, 0);
}

// ---------------------------------------------------------------------------
// Kernel B: pack the three 384x64 fp32 weights into the EXACT per-chunk LDS
// staging order (12 chunks of BK=32):
//   Wp[c][kblk(4)][n(192)][kin(8)] = w_mat(n/64)[(c*32 + kblk*8 + kin)*64 + n%64]
// so qkv staging is 12 fully-contiguous 1-KB global_load_lds per chunk.
// ---------------------------------------------------------------------------
__global__ void prep_w(const float* __restrict__ wq, const float* __restrict__ wk,
                       const float* __restrict__ wv, _Float16* __restrict__ Wp)
{
    int i = blockIdx.x * 256 + threadIdx.x;
    if (i >= 3 * CDIM * HD) return;                 // 73728
    int c    = i / 6144;  int r  = i - c * 6144;    // chunk (BK=32)
    int kblk = r / 1536;  int r2 = r - kblk * 1536;
    int n    = r2 >> 3;   int kin = r2 & 7;
    int k    = c * 32 + kblk * 8 + kin;
    int mat  = n / 64;    int col = n - mat * 64;
    const float* w = (mat == 0) ? wq : ((mat == 1) ? wk : wv);
    Wp[i] = (_Float16)w[k * HD + col];
}

// ---------------------------------------------------------------------------
// Kernel C: fused QKV projection. Block = 128 rows x 192 cols, wave owns
// 32 rows (2 row-groups of 16) x 192 cols -> acc[2][12], B-fragments reused
// across both groups (halves LDS-read traffic vs 16-row waves).
//   x: NEVER staged in LDS -- rows are wave-private, loaded direct to regs
//      (2x float4/lane/group), ping-pong prefetched one chunk ahead; the
//      compiler inserts the minimal vmcnt for the register dependency.
//   W: LDS, TRIPLE-buffered, staged via width-16 global_load_lds with raw
//      s_barrier + counted s_waitcnt vmcnt(N) (T3/T4): the wait at chunk c
//      covers loads issued 2 chunks earlier, so prefetches stay in flight
//      ACROSS barriers (a __syncthreads would drain vmcnt(0) and serialize,
//      which is exactly what capped the previous version at ~57 us).
// vmcnt bookkeeping (program order per chunk: 3x W-stage, 4x x-load, wait):
//   steady state outstanding at the wait = W(c+2)3 + x(c+1)4 = 7 -> vmcnt(7)
//   chunk 10: no W(12) -> vmcnt(4);  chunk 11: nothing new -> vmcnt(0)
// Epilogue: bias + RoPE (fres==1 -> angle=t) via shfl_xor 1; Q scaled.
// Q,K (b,t,d) fp16; V transposed (b,d,t) fp16.
// ---------------------------------------------------------------------------
__global__ __launch_bounds__(256) void qkv_gemm(
    const float* __restrict__ x, const _Float16* __restrict__ Wp,
    const float* __restrict__ bq, const float* __restrict__ bk,
    const float* __restrict__ bv,
    _Float16* __restrict__ Qw, _Float16* __restrict__ Kw,
    _Float16* __restrict__ Vtw, int b0)
{
    __shared__ __align__(16) _Float16 wsb[3][6144];      // 36 KB, triple buffer

    const int tid  = threadIdx.x;
    const int wave = tid >> 6;
    const int lane = tid & 63;
    const int l16  = lane & 15;
    const int quad = lane >> 4;

    const int row0 = blockIdx.x * 128;                   // chunk-local row base
    const size_t rowg = (size_t)b0 * TSEQ + row0;        // global row base

    int woff[3];
#pragma unroll
    for (int i = 0; i < 3; ++i) woff[i] = (wave * 3 + i) * 512 + lane * 8;

    const float* xp[2];
#pragma unroll
    for (int g = 0; g < 2; ++g)
        xp[g] = x + (rowg + wave * 32 + g * 16 + l16) * CDIM + quad * 8;

    floatx4 acc[2][12];
#pragma unroll
    for (int g = 0; g < 2; ++g)
#pragma unroll
        for (int i = 0; i < 12; ++i)
#pragma unroll
            for (int r = 0; r < 4; ++r) acc[g][i][r] = 0.f;

    floatx4 xA[2][2], xB[2][2];                          // ping-pong x regs

#define WSTAGE(cc) do { _Pragma("unroll")                                     \
    for (int i_ = 0; i_ < 3; ++i_)                                            \
        load_lds16(Wp + (size_t)(cc) * 6144 + woff[i_],                       \
                   (char*)&wsb[(cc) % 3][0] + (wave * 3 + i_) * 1024);        \
} while (0)

#define XLOAD(cc, S) do { _Pragma("unroll")                                   \
    for (int g_ = 0; g_ < 2; ++g_) {                                          \
        S[g_][0] = *(const floatx4*)(xp[g_] + (cc) * 32);                     \
        S[g_][1] = *(const floatx4*)(xp[g_] + (cc) * 32 + 4);                 \
    }                                                                         \
} while (0)

#define CHUNK(cc, CUR, NXT, VM) do {                                          \
    if ((cc) + 2 < 12) WSTAGE((cc) + 2);                                      \
    if ((cc) + 1 < 12) XLOAD((cc) + 1, NXT);                                  \
    asm volatile("s_waitcnt vmcnt(" VM ")" ::: "memory");                     \
    half8 aF[2];                                                              \
    _Pragma("unroll")                                                         \
    for (int g_ = 0; g_ < 2; ++g_) {                                          \
        _Pragma("unroll")                                                     \
        for (int jj = 0; jj < 8; ++jj)                                        \
            aF[g_][jj] = (_Float16)(jj < 4 ? CUR[g_][0][jj]                   \
                                           : CUR[g_][1][jj - 4]);             \
    }                                                                         \
    const _Float16* bp = &wsb[(cc) % 3][0] + ((size_t)quad * 192 + l16) * 8;  \
    _Pragma("unroll")                                                         \
    for (int i_ = 0; i_ < 12; ++i_) {                                         \
        half8 bb = *(const half8*)(bp + i_ * 128);                            \
        acc[0][i_] = __builtin_amdgcn_mfma_f32_16x16x32_f16(aF[0], bb, acc[0][i_], 0, 0, 0); \
        acc[1][i_] = __builtin_amdgcn_mfma_f32_16x16x32_f16(aF[1], bb, acc[1][i_], 0, 0, 0); \
    }                                                                         \
    __builtin_amdgcn_s_barrier();                                             \
} while (0)

    // prologue: W(0), W(1), x(0) in flight; wait only W(0) (7 newer remain)
    WSTAGE(0); WSTAGE(1); XLOAD(0, xA);
    asm volatile("s_waitcnt vmcnt(7)" ::: "memory");
    __builtin_amdgcn_s_barrier();

    CHUNK(0,  xA, xB, "7");  CHUNK(1,  xB, xA, "7");
    CHUNK(2,  xA, xB, "7");  CHUNK(3,  xB, xA, "7");
    CHUNK(4,  xA, xB, "7");  CHUNK(5,  xB, xA, "7");
    CHUNK(6,  xA, xB, "7");  CHUNK(7,  xB, xA, "7");
    CHUNK(8,  xA, xB, "7");  CHUNK(9,  xB, xA, "7");
    CHUNK(10, xA, xB, "4");  CHUNK(11, xB, xA, "0");

#undef CHUNK
#undef XLOAD
#undef WSTAGE

    // ---- epilogue: bias + RoPE; Q/K row-major, V transposed (b,d,t) ----
    float bq4[4], bk4[4], bv4[4];
#pragma unroll
    for (int s4 = 0; s4 < 4; ++s4) {
        const int cc = s4 * 16 + l16;
        bq4[s4] = bq[cc]; bk4[s4] = bk[cc]; bv4[s4] = bv[cc];
    }
    const int bidx = row0 >> 9;                          // chunk-local batch
    const int rb   = wave * 32 + quad * 4;

#pragma unroll
    for (int g = 0; g < 2; ++g) {
        const int t00 = (row0 & (TSEQ - 1)) + rb + g * 16;
        const int r00 = row0 + rb + g * 16;
#pragma unroll
        for (int r = 0; r < 4; ++r) {
            const int t = t00 + r;
            const float st = sinf((float)t);
            const float ct = cosf((float)t);
            const int row = r00 + r;
#pragma unroll
            for (int s4 = 0; s4 < 4; ++s4) {
                const int cc = s4 * 16 + l16;
                float vq = acc[g][s4][r] + bq4[s4];
                float pq = __shfl_xor(vq, 1);
                vq = (cc & 1) ? (pq * st + vq * ct) : (vq * ct - pq * st);
                Qw[(size_t)row * HD + cc] = (_Float16)(vq * QSCALE);
                float vk = acc[g][4 + s4][r] + bk4[s4];
                float pk = __shfl_xor(vk, 1);
                vk = (cc & 1) ? (pk * st + vk * ct) : (vk * ct - pk * st);
                Kw[(size_t)row * HD + cc] = (_Float16)vk;
            }
        }
        // V: pack 4 consecutive t per store (t = t00..t00+3 contiguous)
#pragma unroll
        for (int s4 = 0; s4 < 4; ++s4) {
            const int cc = s4 * 16 + l16;
            half4 vpack;
#pragma unroll
            for (int r = 0; r < 4; ++r)
                vpack[r] = (_Float16)(acc[g][8 + s4][r] + bv4[s4]);
            *(half4*)(Vtw + ((size_t)bidx * HD + cc) * TSEQ + t00) = vpack;
        }
    }
}

// ---------------------------------------------------------------------------
// Kernel D: causal flash attention, reduction-free (fixed MBIAS -> partial
// O and L are exactly additive). Grid (8, nb) = 2 blocks/CU, 8 waves/CU.
// Per batch: 16 balanced strip PAIRS (s, 31-s) = constant 9 tile-units each;
// each pair's k-range is split even/odd j between two waves of the same
// block, merged through LDS at the end. K/V fragments for j+2 are register-
// prefetched (ping-pong sets, 2x-unrolled loop, static indexing) so each
// iteration's L2/HBM latency hides under the previous iteration's MFMA+exp.
// Prefetch addresses are clamped to the last valid tile (garbage loads are
// in-bounds and unused). XCD swizzle keeps a batch's 8 blocks on one L2.
// ---------------------------------------------------------------------------
__global__ __launch_bounds__(256, 2) void attn_kernel(
    const _Float16* __restrict__ Qw, const _Float16* __restrict__ Kw,
    const _Float16* __restrict__ Vtw, float* __restrict__ out, int b0)
{
    int bx, bl;
    {
        const int lin = blockIdx.y * 8 + blockIdx.x;
        if ((gridDim.y & 7) == 0) {                  // bijective XCD grouping
            const int per = gridDim.y >> 3;          // batches per XCD
            const int xcd = lin & 7;
            const int k2  = lin >> 3;
            bl = xcd * per + (k2 >> 3);
            bx = k2 & 7;
        } else { bx = blockIdx.x; bl = blockIdx.y; }
    }
    const int tid  = threadIdx.x;
    const int wave = tid >> 6;
    const int lane = tid & 63;
    const int l16  = lane & 15;
    const int quad = lane >> 4;

    const int pr  = bx * 2 + (wave & 1);             // strip pair 0..15
    const int h   = wave >> 1;                       // k-half (even/odd j)
    const int qA  = pr * 16;                         // near strip rows
    const int qB  = (31 - pr) * 16;                  // far strip rows
    const int jdA = pr >> 2;                         // diag tile, strip A
    const int jdB = (31 - pr) >> 2;                  // diag tile, strip B

    __shared__ __align__(16) _Float16 pbuf[4][16][72];
    __shared__ __align__(16) floatx4  mbuf[2][10][64];   // merge buffer

    const _Float16* Qb = Qw  + (size_t)bl * TSEQ * HD;
    const _Float16* Kb = Kw  + (size_t)bl * TSEQ * HD;
    const _Float16* Vb = Vtw + (size_t)bl * HD * TSEQ;   // [d][t]

    half8 aQA0 = *(const half8*)(Qb + (size_t)(qA + l16) * HD + quad * 8);
    half8 aQA1 = *(const half8*)(Qb + (size_t)(qA + l16) * HD + 32 + quad * 8);
    half8 aQB0 = *(const half8*)(Qb + (size_t)(qB + l16) * HD + quad * 8);
    half8 aQB1 = *(const half8*)(Qb + (size_t)(qB + l16) * HD + 32 + quad * 8);

    half8 ones;
#pragma unroll
    for (int jj = 0; jj < 8; ++jj) ones[jj] = (_Float16)1.f;

    floatx4 accO[8], accL[2];
#pragma unroll
    for (int i = 0; i < 8; ++i)
#pragma unroll
        for (int r = 0; r < 4; ++r) accO[i][r] = 0.f;
#pragma unroll
    for (int s = 0; s < 2; ++s)
#pragma unroll
        for (int r = 0; r < 4; ++r) accL[s][r] = 0.f;

    half8 cK0[4], cK1[4], cV0[4], cV1[4];
    half8 nK0[4], nK1[4], nV0[4], nV1[4];

#define KVLOAD(jv, K0, K1, V0, V1) do {                                       \
    const int kb_ = ((jv) * 64 > TSEQ - 64) ? (TSEQ - 64) : (jv) * 64;        \
    _Pragma("unroll")                                                         \
    for (int s4 = 0; s4 < 4; ++s4) {                                          \
        const _Float16* kp = Kb + (size_t)(kb_ + s4 * 16 + l16) * HD + quad * 8; \
        K0[s4] = *(const half8*)(kp);                                         \
        K1[s4] = *(const half8*)(kp + 32);                                    \
        const _Float16* vp = Vb + (size_t)(s4 * 16 + l16) * TSEQ + kb_ + quad * 8; \
        V0[s4] = *(const half8*)(vp);                                         \
        V1[s4] = *(const half8*)(vp + 32);                                    \
    }                                                                         \
} while (0)

#define BODY(jv, K0, K1, V0, V1) do {                                         \
    const int kb = (jv) * 64;                                                 \
    if ((jv) <= jdA) {                                                        \
        floatx4 st4[4];                                                       \
        __builtin_amdgcn_s_setprio(1);                                        \
        _Pragma("unroll")                                                     \
        for (int s4 = 0; s4 < 4; ++s4) {                                      \
            _Pragma("unroll")                                                 \
            for (int r = 0; r < 4; ++r) st4[s4][r] = 0.f;                     \
            st4[s4] = __builtin_amdgcn_mfma_f32_16x16x32_f16(K0[s4], aQA0, st4[s4], 0, 0, 0); \
            st4[s4] = __builtin_amdgcn_mfma_f32_16x16x32_f16(K1[s4], aQA1, st4[s4], 0, 0, 0); \
        }                                                                     \
        __builtin_amdgcn_s_setprio(0);                                        \
        const int qrow = qA + l16;                                            \
        _Pragma("unroll")                                                     \
        for (int s4 = 0; s4 < 4; ++s4) {                                      \
            half4 w;                                                          \
            _Pragma("unroll")                                                 \
            for (int r = 0; r < 4; ++r) {                                     \
                float p = __expf(fminf(st4[s4][r], 18.f) - MBIAS);            \
                if ((jv) == jdA) {                                            \
                    const int kcol = kb + s4 * 16 + quad * 4 + r;             \
                    if (kcol > qrow) p = 0.f;                                 \
                }                                                             \
                w[r] = (_Float16)p;                                           \
            }                                                                 \
            *(half4*)(&pbuf[wave][l16][s4 * 16 + quad * 4]) = w;              \
        }                                                                     \
        half8 aP0 = *(const half8*)(&pbuf[wave][l16][quad * 8]);              \
        half8 aP1 = *(const half8*)(&pbuf[wave][l16][32 + quad * 8]);         \
        __builtin_amdgcn_s_setprio(1);                                        \
        _Pragma("unroll")                                                     \
        for (int s4 = 0; s4 < 4; ++s4) {                                      \
            accO[s4] = __builtin_amdgcn_mfma_f32_16x16x32_f16(aP0, V0[s4], accO[s4], 0, 0, 0); \
            accO[s4] = __builtin_amdgcn_mfma_f32_16x16x32_f16(aP1, V1[s4], accO[s4], 0, 0, 0); \
        }                                                                     \
        accL[0] = __builtin_amdgcn_mfma_f32_16x16x32_f16(aP0, ones, accL[0], 0, 0, 0); \
        accL[0] = __builtin_amdgcn_mfma_f32_16x16x32_f16(aP1, ones, accL[0], 0, 0, 0); \
        __builtin_amdgcn_s_setprio(0);                                        \
    }                                                                         \
    {                                                                         \
        floatx4 st4[4];                                                       \
        __builtin_amdgcn_s_setprio(1);                                        \
        _Pragma("unroll")                                                     \
        for (int s4 = 0; s4 < 4; ++s4) {                                      \
            _Pragma("unroll")                                                 \
            for (int r = 0; r < 4; ++r) st4[s4][r] = 0.f;                     \
            st4[s4] = __builtin_amdgcn_mfma_f32_16x16x32_f16(K0[s4], aQB0, st4[s4], 0, 0, 0); \
            st4[s4] = __builtin_amdgcn_mfma_f32_16x16x32_f16(K1[s4], aQB1, st4[s4], 0, 0, 0); \
        }                                                                     \
        __builtin_amdgcn_s_setprio(0);                                        \
        const int qrow = qB + l16;                                            \
        _Pragma("unroll")                                                     \
        for (int s4 = 0; s4 < 4; ++s4) {                                      \
            half4 w;                                                          \
            _Pragma("unroll")                                                 \
            for (int r = 0; r < 4; ++r) {                                     \
                float p = __expf(fminf(st4[s4][r], 18.f) - MBIAS);            \
                if ((jv) == jdB) {                                            \
                    const int kcol = kb + s4 * 16 + quad * 4 + r;             \
                    if (kcol > qrow) p = 0.f;                                 \
                }                                                             \
                w[r] = (_Float16)p;                                           \
            }                                                                 \
            *(half4*)(&pbuf[wave][l16][s4 * 16 + quad * 4]) = w;              \
        }                                                                     \
        half8 aP0 = *(const half8*)(&pbuf[wave][l16][quad * 8]);              \
        half8 aP1 = *(const half8*)(&pbuf[wave][l16][32 + quad * 8]);         \
        __builtin_amdgcn_s_setprio(1);                                        \
        _Pragma("unroll")                                                     \
        for (int s4 = 0; s4 < 4; ++s4) {                                      \
            accO[4 + s4] = __builtin_amdgcn_mfma_f32_16x16x32_f16(aP0, V0[s4], accO[4 + s4], 0, 0, 0); \
            accO[4 + s4] = __builtin_amdgcn_mfma_f32_16x16x32_f16(aP1, V1[s4], accO[4 + s4], 0, 0, 0); \
        }                                                                     \
        accL[1] = __builtin_amdgcn_mfma_f32_16x16x32_f16(aP0, ones, accL[1], 0, 0, 0); \
        accL[1] = __builtin_amdgcn_mfma_f32_16x16x32_f16(aP1, ones, accL[1], 0, 0, 0); \
        __builtin_amdgcn_s_setprio(0);                                        \
    }                                                                         \
} while (0)

    KVLOAD(h, cK0, cK1, cV0, cV1);
    for (int j = h; j <= jdB; j += 4) {
        KVLOAD(j + 2, nK0, nK1, nV0, nV1);           // prefetch next tile
        BODY(j, cK0, cK1, cV0, cV1);
        KVLOAD(j + 4, cK0, cK1, cV0, cV1);           // prefetch tile after
        if (j + 2 <= jdB) BODY(j + 2, nK0, nK1, nV0, nV1);
    }
#undef BODY
#undef KVLOAD

    // ---- merge the two k-halves of each pair (exact: fixed-bias softmax) --
    const int slot = wave & 1;
    if (h == 1) {
#pragma unroll
        for (int i = 0; i < 8; ++i) mbuf[slot][i][lane] = accO[i];
        mbuf[slot][8][lane] = accL[0];
        mbuf[slot][9][lane] = accL[1];
    }
    __syncthreads();
    if (h == 1) return;

#pragma unroll
    for (int i = 0; i < 8; ++i) {
        floatx4 t = mbuf[slot][i][lane];
#pragma unroll
        for (int r = 0; r < 4; ++r) accO[i][r] += t[r];
    }
    {
        floatx4 t8 = mbuf[slot][8][lane];
        floatx4 t9 = mbuf[slot][9][lane];
#pragma unroll
        for (int r = 0; r < 4; ++r) { accL[0][r] += t8[r]; accL[1][r] += t9[r]; }
    }

    // ---- epilogue (h==0 wave writes both strips) ----
#pragma unroll
    for (int s = 0; s < 2; ++s) {
        const int qbase = (s == 0) ? qA : qB;
        float inv[4];
#pragma unroll
        for (int r = 0; r < 4; ++r) inv[r] = 1.f / accL[s][r];
#pragma unroll
        for (int s4 = 0; s4 < 4; ++s4) {
            const int dcol = s4 * 16 + l16;
#pragma unroll
            for (int r = 0; r < 4; ++r) {
                const int qr = qbase + quad * 4 + r;
                out[((size_t)(b0 + bl) * TSEQ + qr) * HD + dcol] =
                    accO[s * 4 + s4][r] * inv[r];
            }
        }
    }
}

// ---------------------------------------------------------------------------
extern "C" void kernel_launch(void* const* d_in, const int* in_sizes, int n_in,
                              void* d_out, int out_size, void* d_ws, size_t ws_size,
                              hipStream_t stream)
{
    char* ws = (char*)d_ws;
    _Float16* Wp = (_Float16*)ws;                           // 147456 B
    char* qkv_base = ws + 147456;

    const size_t per_b = (size_t)3 * TSEQ * HD * sizeof(_Float16);  // 196608 B
    size_t avail = (ws_size > (size_t)147456) ? ws_size - 147456 : per_b;
    int nbc = (int)(avail / per_b);
    if (nbc > NB) nbc = NB;
    if (nbc < 1)  nbc = 1;

    const size_t chunk_elems = (size_t)nbc * TSEQ * HD;
    _Float16* Qw  = (_Float16*)qkv_base;
    _Float16* Kw  = Qw + chunk_elems;
    _Float16* Vtw = Kw + chunk_elems;

    prep_w<<<dim3((3 * CDIM * HD + 255) / 256), dim3(256), 0, stream>>>(
        (const float*)d_in[1], (const float*)d_in[3], (const float*)d_in[5], Wp);

    for (int b0 = 0; b0 < NB; b0 += nbc) {
        const int nb = (NB - b0 < nbc) ? (NB - b0) : nbc;
        qkv_gemm<<<dim3(nb * 4), dim3(256), 0, stream>>>(
            (const float*)d_in[0], Wp, (const float*)d_in[2], (const float*)d_in[4],
            (const float*)d_in[6], Qw, Kw, Vtw, b0);
        attn_kernel<<<dim3(8, nb), dim3(256), 0, stream>>>(
            Qw, Kw, Vtw, (float*)d_out, b0);
    }
}

// Round 3
// 211.198 us; speedup vs baseline: 1.0440x; 1.0440x over previous
//
#include <hip/hip_runtime.h>

#define TSEQ 512
#define NB   128
#define CDIM 384
#define HD   64
#define QSCALE 0.051031036307982884f   // 384^-0.5, folded into Q at projection
#define MBIAS  8.0f                    // fixed softmax offset (exact: cancels in O=PV/l)

typedef _Float16 half8  __attribute__((ext_vector_type(8)));
typedef _Float16 half4  __attribute__((ext_vector_type(4)));
typedef float    floatx4 __attribute__((ext_vector_type(4)));

typedef __attribute__((address_space(3))) unsigned int lds_u32;
typedef const __attribute__((address_space(1))) unsigned int g_u32;

__device__ __forceinline__ void load_lds16(const void* g, void* l) {
    // async global->LDS DMA, 16B/lane; LDS dst = wave-uniform base + lane*16
    __builtin_amdgcn_global_load_lds((g_u32*)g, (lds_u32*)l, 16, 0, 0);
}

// ---------------------------------------------------------------------------
// Kernel B: pack the three 384x64 fp32 weights into the EXACT per-chunk LDS
// staging order (12 chunks of BK=32):
//   Wp[c][kblk(4)][n(192)][kin(8)] = w_mat(n/64)[(c*32 + kblk*8 + kin)*64 + n%64]
// so qkv staging is 12 fully-contiguous 1-KB global_load_lds per chunk.
// ---------------------------------------------------------------------------
__global__ void prep_w(const float* __restrict__ wq, const float* __restrict__ wk,
                       const float* __restrict__ wv, _Float16* __restrict__ Wp)
{
    int i = blockIdx.x * 256 + threadIdx.x;
    if (i >= 3 * CDIM * HD) return;                 // 73728
    int c    = i / 6144;  int r  = i - c * 6144;    // chunk (BK=32)
    int kblk = r / 1536;  int r2 = r - kblk * 1536;
    int n    = r2 >> 3;   int kin = r2 & 7;
    int k    = c * 32 + kblk * 8 + kin;
    int mat  = n / 64;    int col = n - mat * 64;
    const float* w = (mat == 0) ? wq : ((mat == 1) ? wk : wv);
    Wp[i] = (_Float16)w[k * HD + col];
}

// ---------------------------------------------------------------------------
// Kernel C: fused QKV projection (UNCHANGED from round 2 -- the A/B this
// round isolates it). Block = 128 rows x 192 cols, wave owns 32 rows
// (2 row-groups of 16) x 192 cols -> acc[2][12], B-fragments reused across
// both groups.
//   x: direct to registers (wave-private rows), ping-pong one chunk ahead.
//   W: LDS, TRIPLE-buffered, width-16 global_load_lds + raw s_barrier +
//      counted s_waitcnt vmcnt(N) (T3/T4): the wait at chunk c covers loads
//      issued 2 chunks earlier, so prefetches stay in flight ACROSS barriers.
// vmcnt bookkeeping (program order per chunk: 3x W-stage, 4x x-load, wait):
//   steady state outstanding at the wait = W(c+2)3 + x(c+1)4 = 7 -> vmcnt(7)
//   chunk 10: no W(12) -> vmcnt(4);  chunk 11: nothing new -> vmcnt(0)
// Epilogue: bias + RoPE (fres==1 -> angle=t) via shfl_xor 1; Q scaled.
// Q,K (b,t,d) fp16; V transposed (b,d,t) fp16.
// ---------------------------------------------------------------------------
__global__ __launch_bounds__(256) void qkv_gemm(
    const float* __restrict__ x, const _Float16* __restrict__ Wp,
    const float* __restrict__ bq, const float* __restrict__ bk,
    const float* __restrict__ bv,
    _Float16* __restrict__ Qw, _Float16* __restrict__ Kw,
    _Float16* __restrict__ Vtw, int b0)
{
    __shared__ __align__(16) _Float16 wsb[3][6144];      // 36 KB, triple buffer

    const int tid  = threadIdx.x;
    const int wave = tid >> 6;
    const int lane = tid & 63;
    const int l16  = lane & 15;
    const int quad = lane >> 4;

    const int row0 = blockIdx.x * 128;                   // chunk-local row base
    const size_t rowg = (size_t)b0 * TSEQ + row0;        // global row base

    int woff[3];
#pragma unroll
    for (int i = 0; i < 3; ++i) woff[i] = (wave * 3 + i) * 512 + lane * 8;

    const float* xp[2];
#pragma unroll
    for (int g = 0; g < 2; ++g)
        xp[g] = x + (rowg + wave * 32 + g * 16 + l16) * CDIM + quad * 8;

    floatx4 acc[2][12];
#pragma unroll
    for (int g = 0; g < 2; ++g)
#pragma unroll
        for (int i = 0; i < 12; ++i)
#pragma unroll
            for (int r = 0; r < 4; ++r) acc[g][i][r] = 0.f;

    floatx4 xA[2][2], xB[2][2];                          // ping-pong x regs

#define WSTAGE(cc) do { _Pragma("unroll")                                     \
    for (int i_ = 0; i_ < 3; ++i_)                                            \
        load_lds16(Wp + (size_t)(cc) * 6144 + woff[i_],                       \
                   (char*)&wsb[(cc) % 3][0] + (wave * 3 + i_) * 1024);        \
} while (0)

#define XLOAD(cc, S) do { _Pragma("unroll")                                   \
    for (int g_ = 0; g_ < 2; ++g_) {                                          \
        S[g_][0] = *(const floatx4*)(xp[g_] + (cc) * 32);                     \
        S[g_][1] = *(const floatx4*)(xp[g_] + (cc) * 32 + 4);                 \
    }                                                                         \
} while (0)

#define CHUNK(cc, CUR, NXT, VM) do {                                          \
    if ((cc) + 2 < 12) WSTAGE((cc) + 2);                                      \
    if ((cc) + 1 < 12) XLOAD((cc) + 1, NXT);                                  \
    asm volatile("s_waitcnt vmcnt(" VM ")" ::: "memory");                     \
    half8 aF[2];                                                              \
    _Pragma("unroll")                                                         \
    for (int g_ = 0; g_ < 2; ++g_) {                                          \
        _Pragma("unroll")                                                     \
        for (int jj = 0; jj < 8; ++jj)                                        \
            aF[g_][jj] = (_Float16)(jj < 4 ? CUR[g_][0][jj]                   \
                                           : CUR[g_][1][jj - 4]);             \
    }                                                                         \
    const _Float16* bp = &wsb[(cc) % 3][0] + ((size_t)quad * 192 + l16) * 8;  \
    _Pragma("unroll")                                                         \
    for (int i_ = 0; i_ < 12; ++i_) {                                         \
        half8 bb = *(const half8*)(bp + i_ * 128);                            \
        acc[0][i_] = __builtin_amdgcn_mfma_f32_16x16x32_f16(aF[0], bb, acc[0][i_], 0, 0, 0); \
        acc[1][i_] = __builtin_amdgcn_mfma_f32_16x16x32_f16(aF[1], bb, acc[1][i_], 0, 0, 0); \
    }                                                                         \
    __builtin_amdgcn_s_barrier();                                             \
} while (0)

    // prologue: W(0), W(1), x(0) in flight; wait only W(0) (7 newer remain)
    WSTAGE(0); WSTAGE(1); XLOAD(0, xA);
    asm volatile("s_waitcnt vmcnt(7)" ::: "memory");
    __builtin_amdgcn_s_barrier();

    CHUNK(0,  xA, xB, "7");  CHUNK(1,  xB, xA, "7");
    CHUNK(2,  xA, xB, "7");  CHUNK(3,  xB, xA, "7");
    CHUNK(4,  xA, xB, "7");  CHUNK(5,  xB, xA, "7");
    CHUNK(6,  xA, xB, "7");  CHUNK(7,  xB, xA, "7");
    CHUNK(8,  xA, xB, "7");  CHUNK(9,  xB, xA, "7");
    CHUNK(10, xA, xB, "4");  CHUNK(11, xB, xA, "0");

#undef CHUNK
#undef XLOAD
#undef WSTAGE

    // ---- epilogue: bias + RoPE; Q/K row-major, V transposed (b,d,t) ----
    float bq4[4], bk4[4], bv4[4];
#pragma unroll
    for (int s4 = 0; s4 < 4; ++s4) {
        const int cc = s4 * 16 + l16;
        bq4[s4] = bq[cc]; bk4[s4] = bk[cc]; bv4[s4] = bv[cc];
    }
    const int bidx = row0 >> 9;                          // chunk-local batch
    const int rb   = wave * 32 + quad * 4;

#pragma unroll
    for (int g = 0; g < 2; ++g) {
        const int t00 = (row0 & (TSEQ - 1)) + rb + g * 16;
        const int r00 = row0 + rb + g * 16;
#pragma unroll
        for (int r = 0; r < 4; ++r) {
            const int t = t00 + r;
            const float st = sinf((float)t);
            const float ct = cosf((float)t);
            const int row = r00 + r;
#pragma unroll
            for (int s4 = 0; s4 < 4; ++s4) {
                const int cc = s4 * 16 + l16;
                float vq = acc[g][s4][r] + bq4[s4];
                float pq = __shfl_xor(vq, 1);
                vq = (cc & 1) ? (pq * st + vq * ct) : (vq * ct - pq * st);
                Qw[(size_t)row * HD + cc] = (_Float16)(vq * QSCALE);
                float vk = acc[g][4 + s4][r] + bk4[s4];
                float pk = __shfl_xor(vk, 1);
                vk = (cc & 1) ? (pk * st + vk * ct) : (vk * ct - pk * st);
                Kw[(size_t)row * HD + cc] = (_Float16)vk;
            }
        }
        // V: pack 4 consecutive t per store (t = t00..t00+3 contiguous)
#pragma unroll
        for (int s4 = 0; s4 < 4; ++s4) {
            const int cc = s4 * 16 + l16;
            half4 vpack;
#pragma unroll
            for (int r = 0; r < 4; ++r)
                vpack[r] = (_Float16)(acc[g][8 + s4][r] + bv4[s4]);
            *(half4*)(Vtw + ((size_t)bidx * HD + cc) * TSEQ + t00) = vpack;
        }
    }
}

// ---------------------------------------------------------------------------
// Kernel D: causal flash attention, reduction-free (fixed MBIAS -> partial
// O and L are exactly additive). REVERTED to round-1 (no KV register
// prefetch: the two-set ping-pong put live state near the VGPR cap and is
// the prime suspect for round-2's +10us). Grid (8, nb) = 2 blocks/CU.
// Per batch: 16 balanced strip PAIRS (s, 31-s) = constant 9 tile-units each;
// each pair's k-range is split even/odd j between two waves of the same
// block, merged through LDS at the end. XCD swizzle keeps a batch's 8
// blocks on one XCD (K/V stays in one L2).
// ---------------------------------------------------------------------------
__global__ __launch_bounds__(256) void attn_kernel(
    const _Float16* __restrict__ Qw, const _Float16* __restrict__ Kw,
    const _Float16* __restrict__ Vtw, float* __restrict__ out, int b0)
{
    int bx, bl;
    {
        const int lin = blockIdx.y * 8 + blockIdx.x;
        if ((gridDim.y & 7) == 0) {                  // bijective XCD grouping
            const int per = gridDim.y >> 3;          // batches per XCD
            const int xcd = lin & 7;
            const int k2  = lin >> 3;
            bl = xcd * per + (k2 >> 3);
            bx = k2 & 7;
        } else { bx = blockIdx.x; bl = blockIdx.y; }
    }
    const int tid  = threadIdx.x;
    const int wave = tid >> 6;
    const int lane = tid & 63;
    const int l16  = lane & 15;
    const int quad = lane >> 4;

    const int pr  = bx * 2 + (wave & 1);             // strip pair 0..15
    const int h   = wave >> 1;                       // k-half (even/odd j)
    const int qA  = pr * 16;                         // near strip rows
    const int qB  = (31 - pr) * 16;                  // far strip rows
    const int jdA = pr >> 2;                         // diag tile, strip A
    const int jdB = (31 - pr) >> 2;                  // diag tile, strip B

    __shared__ __align__(16) _Float16 pbuf[4][16][72];
    __shared__ __align__(16) floatx4  mbuf[2][10][64];   // merge buffer

    const _Float16* Qb = Qw  + (size_t)bl * TSEQ * HD;
    const _Float16* Kb = Kw  + (size_t)bl * TSEQ * HD;
    const _Float16* Vb = Vtw + (size_t)bl * HD * TSEQ;   // [d][t]

    half8 aQA0 = *(const half8*)(Qb + (size_t)(qA + l16) * HD + quad * 8);
    half8 aQA1 = *(const half8*)(Qb + (size_t)(qA + l16) * HD + 32 + quad * 8);
    half8 aQB0 = *(const half8*)(Qb + (size_t)(qB + l16) * HD + quad * 8);
    half8 aQB1 = *(const half8*)(Qb + (size_t)(qB + l16) * HD + 32 + quad * 8);

    half8 ones;
#pragma unroll
    for (int jj = 0; jj < 8; ++jj) ones[jj] = (_Float16)1.f;

    floatx4 accO[8], accL[2];
#pragma unroll
    for (int i = 0; i < 8; ++i)
#pragma unroll
        for (int r = 0; r < 4; ++r) accO[i][r] = 0.f;
#pragma unroll
    for (int s = 0; s < 2; ++s)
#pragma unroll
        for (int r = 0; r < 4; ++r) accL[s][r] = 0.f;

    for (int j = h; j <= jdB; j += 2) {
        const int kb = j * 64;

        // ---- shared K/V fragment loads (amortized across both strips) ----
        half8 bK0[4], bK1[4], bV0[4], bV1[4];
#pragma unroll
        for (int s4 = 0; s4 < 4; ++s4) {
            const _Float16* kp = Kb + (size_t)(kb + s4 * 16 + l16) * HD + quad * 8;
            bK0[s4] = *(const half8*)(kp);
            bK1[s4] = *(const half8*)(kp + 32);
            const _Float16* vp = Vb + (size_t)(s4 * 16 + l16) * TSEQ + kb + quad * 8;
            bV0[s4] = *(const half8*)(vp);
            bV1[s4] = *(const half8*)(vp + 32);
        }

        // ================= strip A (near; inactive past its diagonal) =====
        if (j <= jdA) {
            floatx4 st4[4];
            __builtin_amdgcn_s_setprio(1);
#pragma unroll
            for (int s4 = 0; s4 < 4; ++s4) {
#pragma unroll
                for (int r = 0; r < 4; ++r) st4[s4][r] = 0.f;
                st4[s4] = __builtin_amdgcn_mfma_f32_16x16x32_f16(bK0[s4], aQA0, st4[s4], 0, 0, 0);
                st4[s4] = __builtin_amdgcn_mfma_f32_16x16x32_f16(bK1[s4], aQA1, st4[s4], 0, 0, 0);
            }
            __builtin_amdgcn_s_setprio(0);
            const int qrow = qA + l16;
#pragma unroll
            for (int s4 = 0; s4 < 4; ++s4) {
                half4 w;
#pragma unroll
                for (int r = 0; r < 4; ++r) {
                    float p = __expf(fminf(st4[s4][r], 18.f) - MBIAS);
                    if (j == jdA) {
                        const int kcol = kb + s4 * 16 + quad * 4 + r;
                        if (kcol > qrow) p = 0.f;
                    }
                    w[r] = (_Float16)p;
                }
                *(half4*)(&pbuf[wave][l16][s4 * 16 + quad * 4]) = w;
            }
            half8 aP0 = *(const half8*)(&pbuf[wave][l16][quad * 8]);
            half8 aP1 = *(const half8*)(&pbuf[wave][l16][32 + quad * 8]);
            __builtin_amdgcn_s_setprio(1);
#pragma unroll
            for (int s4 = 0; s4 < 4; ++s4) {
                accO[s4] = __builtin_amdgcn_mfma_f32_16x16x32_f16(aP0, bV0[s4], accO[s4], 0, 0, 0);
                accO[s4] = __builtin_amdgcn_mfma_f32_16x16x32_f16(aP1, bV1[s4], accO[s4], 0, 0, 0);
            }
            accL[0] = __builtin_amdgcn_mfma_f32_16x16x32_f16(aP0, ones, accL[0], 0, 0, 0);
            accL[0] = __builtin_amdgcn_mfma_f32_16x16x32_f16(aP1, ones, accL[0], 0, 0, 0);
            __builtin_amdgcn_s_setprio(0);
        }

        // ================= strip B (far) ==================================
        {
            floatx4 st4[4];
            __builtin_amdgcn_s_setprio(1);
#pragma unroll
            for (int s4 = 0; s4 < 4; ++s4) {
#pragma unroll
                for (int r = 0; r < 4; ++r) st4[s4][r] = 0.f;
                st4[s4] = __builtin_amdgcn_mfma_f32_16x16x32_f16(bK0[s4], aQB0, st4[s4], 0, 0, 0);
                st4[s4] = __builtin_amdgcn_mfma_f32_16x16x32_f16(bK1[s4], aQB1, st4[s4], 0, 0, 0);
            }
            __builtin_amdgcn_s_setprio(0);
            const int qrow = qB + l16;
#pragma unroll
            for (int s4 = 0; s4 < 4; ++s4) {
                half4 w;
#pragma unroll
                for (int r = 0; r < 4; ++r) {
                    float p = __expf(fminf(st4[s4][r], 18.f) - MBIAS);
                    if (j == jdB) {
                        const int kcol = kb + s4 * 16 + quad * 4 + r;
                        if (kcol > qrow) p = 0.f;
                    }
                    w[r] = (_Float16)p;
                }
                *(half4*)(&pbuf[wave][l16][s4 * 16 + quad * 4]) = w;
            }
            half8 aP0 = *(const half8*)(&pbuf[wave][l16][quad * 8]);
            half8 aP1 = *(const half8*)(&pbuf[wave][l16][32 + quad * 8]);
            __builtin_amdgcn_s_setprio(1);
#pragma unroll
            for (int s4 = 0; s4 < 4; ++s4) {
                accO[4 + s4] = __builtin_amdgcn_mfma_f32_16x16x32_f16(aP0, bV0[s4], accO[4 + s4], 0, 0, 0);
                accO[4 + s4] = __builtin_amdgcn_mfma_f32_16x16x32_f16(aP1, bV1[s4], accO[4 + s4], 0, 0, 0);
            }
            accL[1] = __builtin_amdgcn_mfma_f32_16x16x32_f16(aP0, ones, accL[1], 0, 0, 0);
            accL[1] = __builtin_amdgcn_mfma_f32_16x16x32_f16(aP1, ones, accL[1], 0, 0, 0);
            __builtin_amdgcn_s_setprio(0);
        }
    }

    // ---- merge the two k-halves of each pair (exact: fixed-bias softmax) --
    const int slot = wave & 1;
    if (h == 1) {
#pragma unroll
        for (int i = 0; i < 8; ++i) mbuf[slot][i][lane] = accO[i];
        mbuf[slot][8][lane] = accL[0];
        mbuf[slot][9][lane] = accL[1];
    }
    __syncthreads();
    if (h == 1) return;

#pragma unroll
    for (int i = 0; i < 8; ++i) {
        floatx4 t = mbuf[slot][i][lane];
#pragma unroll
        for (int r = 0; r < 4; ++r) accO[i][r] += t[r];
    }
    {
        floatx4 t8 = mbuf[slot][8][lane];
        floatx4 t9 = mbuf[slot][9][lane];
#pragma unroll
        for (int r = 0; r < 4; ++r) { accL[0][r] += t8[r]; accL[1][r] += t9[r]; }
    }

    // ---- epilogue (h==0 wave writes both strips) ----
#pragma unroll
    for (int s = 0; s < 2; ++s) {
        const int qbase = (s == 0) ? qA : qB;
        float inv[4];
#pragma unroll
        for (int r = 0; r < 4; ++r) inv[r] = 1.f / accL[s][r];
#pragma unroll
        for (int s4 = 0; s4 < 4; ++s4) {
            const int dcol = s4 * 16 + l16;
#pragma unroll
            for (int r = 0; r < 4; ++r) {
                const int qr = qbase + quad * 4 + r;
                out[((size_t)(b0 + bl) * TSEQ + qr) * HD + dcol] =
                    accO[s * 4 + s4][r] * inv[r];
            }
        }
    }
}

// ---------------------------------------------------------------------------
extern "C" void kernel_launch(void* const* d_in, const int* in_sizes, int n_in,
                              void* d_out, int out_size, void* d_ws, size_t ws_size,
                              hipStream_t stream)
{
    char* ws = (char*)d_ws;
    _Float16* Wp = (_Float16*)ws;                           // 147456 B
    char* qkv_base = ws + 147456;

    const size_t per_b = (size_t)3 * TSEQ * HD * sizeof(_Float16);  // 196608 B
    size_t avail = (ws_size > (size_t)147456) ? ws_size - 147456 : per_b;
    int nbc = (int)(avail / per_b);
    if (nbc > NB) nbc = NB;
    if (nbc < 1)  nbc = 1;

    const size_t chunk_elems = (size_t)nbc * TSEQ * HD;
    _Float16* Qw  = (_Float16*)qkv_base;
    _Float16* Kw  = Qw + chunk_elems;
    _Float16* Vtw = Kw + chunk_elems;

    prep_w<<<dim3((3 * CDIM * HD + 255) / 256), dim3(256), 0, stream>>>(
        (const float*)d_in[1], (const float*)d_in[3], (const float*)d_in[5], Wp);

    for (int b0 = 0; b0 < NB; b0 += nbc) {
        const int nb = (NB - b0 < nbc) ? (NB - b0) : nbc;
        qkv_gemm<<<dim3(nb * 4), dim3(256), 0, stream>>>(
            (const float*)d_in[0], Wp, (const float*)d_in[2], (const float*)d_in[4],
            (const float*)d_in[6], Qw, Kw, Vtw, b0);
        attn_kernel<<<dim3(8, nb), dim3(256), 0, stream>>>(
            Qw, Kw, Vtw, (float*)d_out, b0);
    }
}

// Round 4
// 207.744 us; speedup vs baseline: 1.0613x; 1.0166x over previous
//
#include <hip/hip_runtime.h>

#define TSEQ 512
#define NB   128
#define CDIM 384
#define HD   64
#define QSCALE 0.051031036307982884f   // 384^-0.5, folded into Q at projection
#define MBIAS  8.0f                    // fixed softmax offset (exact: cancels in O=PV/l)

typedef _Float16 half8  __attribute__((ext_vector_type(8)));
typedef _Float16 half4  __attribute__((ext_vector_type(4)));
typedef float    floatx4 __attribute__((ext_vector_type(4)));

typedef __attribute__((address_space(3))) unsigned int lds_u32;
typedef const __attribute__((address_space(1))) unsigned int g_u32;

__device__ __forceinline__ void load_lds16(const void* g, void* l) {
    // async global->LDS DMA, 16B/lane; LDS dst = wave-uniform base + lane*16
    __builtin_amdgcn_global_load_lds((g_u32*)g, (lds_u32*)l, 16, 0, 0);
}

// ---------------------------------------------------------------------------
// Kernel B: pack the three 384x64 fp32 weights into the EXACT per-chunk LDS
// staging order (12 chunks of BK=32):
//   Wp[c][kblk(4)][n(192)][kin(8)] = w_mat(n/64)[(c*32 + kblk*8 + kin)*64 + n%64]
// so qkv staging is 12 fully-contiguous 1-KB global_load_lds per chunk.
// ---------------------------------------------------------------------------
__global__ void prep_w(const float* __restrict__ wq, const float* __restrict__ wk,
                       const float* __restrict__ wv, _Float16* __restrict__ Wp)
{
    int i = blockIdx.x * 256 + threadIdx.x;
    if (i >= 3 * CDIM * HD) return;                 // 73728
    int c    = i / 6144;  int r  = i - c * 6144;    // chunk (BK=32)
    int kblk = r / 1536;  int r2 = r - kblk * 1536;
    int n    = r2 >> 3;   int kin = r2 & 7;
    int k    = c * 32 + kblk * 8 + kin;
    int mat  = n / 64;    int col = n - mat * 64;
    const float* w = (mat == 0) ? wq : ((mat == 1) ? wk : wv);
    Wp[i] = (_Float16)w[k * HD + col];
}

// ---------------------------------------------------------------------------
// Kernel C: fused QKV projection -- OCCUPANCY round. Same counted-vmcnt
// pipeline as round 3 (proven correct, neutral perf), but 64-row blocks:
// grid = nb*8 = 1024 blocks -> 4 blocks/CU (LDS 36 KB) x 4 waves =
// 16 waves/CU, 2x round-3 residency. __launch_bounds__(256,4) caps VGPR
// at 128 so the 4-blocks/CU target is register-feasible (acc is now 12
// f32x4 = 48 VGPR). Theory: qkv is latency-bound on cold x/W reads (fills
// evict L2/L3 each iteration); TLP is the untested axis.
//   x: direct to registers, ping-pong one chunk ahead (2 float4/lane).
//   W: LDS triple-buffer, width-16 global_load_lds + raw s_barrier +
//      counted s_waitcnt vmcnt(N) -- loads stay in flight across barriers.
// vmcnt bookkeeping (per chunk: 3x W-stage, 2x x-load, wait):
//   steady: outstanding at wait = W(c+2)3 + x(c+1)2 = 5 -> vmcnt(5)
//   chunk 10: no W(12) -> vmcnt(2);  chunk 11: nothing new -> vmcnt(0)
// Epilogue: bias + RoPE (fres==1 -> angle=t) via shfl_xor 1; Q scaled.
// Q,K (b,t,d) fp16; V transposed (b,d,t) fp16.
// ---------------------------------------------------------------------------
__global__ __launch_bounds__(256, 4) void qkv_gemm(
    const float* __restrict__ x, const _Float16* __restrict__ Wp,
    const float* __restrict__ bq, const float* __restrict__ bk,
    const float* __restrict__ bv,
    _Float16* __restrict__ Qw, _Float16* __restrict__ Kw,
    _Float16* __restrict__ Vtw, int b0)
{
    __shared__ __align__(16) _Float16 wsb[3][6144];      // 36 KB, triple buffer

    const int tid  = threadIdx.x;
    const int wave = tid >> 6;
    const int lane = tid & 63;
    const int l16  = lane & 15;
    const int quad = lane >> 4;

    const int row0 = blockIdx.x * 64;                    // chunk-local row base
    const size_t rowg = (size_t)b0 * TSEQ + row0;        // global row base

    int woff[3];
#pragma unroll
    for (int i = 0; i < 3; ++i) woff[i] = (wave * 3 + i) * 512 + lane * 8;

    const float* xp = x + (rowg + wave * 16 + l16) * CDIM + quad * 8;

    floatx4 acc[12];
#pragma unroll
    for (int i = 0; i < 12; ++i)
#pragma unroll
        for (int r = 0; r < 4; ++r) acc[i][r] = 0.f;

    floatx4 xA[2], xB[2];                                // ping-pong x regs

#define WSTAGE(cc) do { _Pragma("unroll")                                     \
    for (int i_ = 0; i_ < 3; ++i_)                                            \
        load_lds16(Wp + (size_t)(cc) * 6144 + woff[i_],                       \
                   (char*)&wsb[(cc) % 3][0] + (wave * 3 + i_) * 1024);        \
} while (0)

#define XLOAD(cc, S) do {                                                     \
    S[0] = *(const floatx4*)(xp + (cc) * 32);                                 \
    S[1] = *(const floatx4*)(xp + (cc) * 32 + 4);                             \
} while (0)

#define CHUNK(cc, CUR, NXT, VM) do {                                          \
    if ((cc) + 2 < 12) WSTAGE((cc) + 2);                                      \
    if ((cc) + 1 < 12) XLOAD((cc) + 1, NXT);                                  \
    asm volatile("s_waitcnt vmcnt(" VM ")" ::: "memory");                     \
    half8 aF;                                                                 \
    _Pragma("unroll")                                                         \
    for (int jj = 0; jj < 8; ++jj)                                            \
        aF[jj] = (_Float16)(jj < 4 ? CUR[0][jj] : CUR[1][jj - 4]);            \
    const _Float16* bp = &wsb[(cc) % 3][0] + ((size_t)quad * 192 + l16) * 8;  \
    _Pragma("unroll")                                                         \
    for (int i_ = 0; i_ < 12; ++i_) {                                         \
        half8 bb = *(const half8*)(bp + i_ * 128);                            \
        acc[i_] = __builtin_amdgcn_mfma_f32_16x16x32_f16(aF, bb, acc[i_], 0, 0, 0); \
    }                                                                         \
    __builtin_amdgcn_s_barrier();                                             \
} while (0)

    // prologue: W(0)3, W(1)3, x(0)2 in flight; wait W(0) -> 5 newer remain
    WSTAGE(0); WSTAGE(1); XLOAD(0, xA);
    asm volatile("s_waitcnt vmcnt(5)" ::: "memory");
    __builtin_amdgcn_s_barrier();

    CHUNK(0,  xA, xB, "5");  CHUNK(1,  xB, xA, "5");
    CHUNK(2,  xA, xB, "5");  CHUNK(3,  xB, xA, "5");
    CHUNK(4,  xA, xB, "5");  CHUNK(5,  xB, xA, "5");
    CHUNK(6,  xA, xB, "5");  CHUNK(7,  xB, xA, "5");
    CHUNK(8,  xA, xB, "5");  CHUNK(9,  xB, xA, "5");
    CHUNK(10, xA, xB, "2");  CHUNK(11, xB, xA, "0");

#undef CHUNK
#undef XLOAD
#undef WSTAGE

    // ---- epilogue: bias + RoPE; Q/K row-major, V transposed (b,d,t) ----
    float bq4[4], bk4[4], bv4[4];
#pragma unroll
    for (int s4 = 0; s4 < 4; ++s4) {
        const int cc = s4 * 16 + l16;
        bq4[s4] = bq[cc]; bk4[s4] = bk[cc]; bv4[s4] = bv[cc];
    }
    const int bidx = row0 >> 9;                          // chunk-local batch
    const int t00  = (row0 & (TSEQ - 1)) + wave * 16 + quad * 4;
    const int rowb = row0 + wave * 16 + quad * 4;

#pragma unroll
    for (int r = 0; r < 4; ++r) {
        const int t = t00 + r;
        const float st = sinf((float)t);
        const float ct = cosf((float)t);
        const int row = rowb + r;
#pragma unroll
        for (int s4 = 0; s4 < 4; ++s4) {
            const int cc = s4 * 16 + l16;
            float vq = acc[s4][r] + bq4[s4];
            float pq = __shfl_xor(vq, 1);
            vq = (cc & 1) ? (pq * st + vq * ct) : (vq * ct - pq * st);
            Qw[(size_t)row * HD + cc] = (_Float16)(vq * QSCALE);
            float vk = acc[4 + s4][r] + bk4[s4];
            float pk = __shfl_xor(vk, 1);
            vk = (cc & 1) ? (pk * st + vk * ct) : (vk * ct - pk * st);
            Kw[(size_t)row * HD + cc] = (_Float16)vk;
        }
    }
    // V: pack 4 consecutive t per store (t = t00..t00+3 contiguous)
#pragma unroll
    for (int s4 = 0; s4 < 4; ++s4) {
        const int cc = s4 * 16 + l16;
        half4 vpack;
#pragma unroll
        for (int r = 0; r < 4; ++r) vpack[r] = (_Float16)(acc[8 + s4][r] + bv4[s4]);
        *(half4*)(Vtw + ((size_t)bidx * HD + cc) * TSEQ + t00) = vpack;
    }
}

// ---------------------------------------------------------------------------
// Kernel D: causal flash attention -- OCCUPANCY round. Grid (16, nb) =
// 2048 blocks; each block owns ONE balanced strip pair (pr, 31-pr) = 9
// tile-units; its 4 waves split the k-range by j mod 4 and merge through
// LDS at the end (exact: fixed-bias softmax makes partials additive).
// V is loaded AFTER K's QK^T consumes it, so K and V fragment sets never
// coexist (-32 live VGPR); __launch_bounds__(256,3) targets >=12 waves/CU
// (vs ~8 before). Theory: attn is latency-bound on cold K/V reads; TLP.
// XCD swizzle keeps a batch's 16 blocks on one XCD (K/V stays in one L2).
// ---------------------------------------------------------------------------
__global__ __launch_bounds__(256, 3) void attn_kernel(
    const _Float16* __restrict__ Qw, const _Float16* __restrict__ Kw,
    const _Float16* __restrict__ Vtw, float* __restrict__ out, int b0)
{
    int bx, bl;
    {
        const int lin = blockIdx.y * 16 + blockIdx.x;
        if ((gridDim.y & 7) == 0) {                  // bijective XCD grouping
            const int per = gridDim.y >> 3;          // batches per XCD
            const int xcd = lin & 7;
            const int k2  = lin >> 3;                // [0, 2*nb)
            bl = xcd * per + (k2 >> 4);
            bx = k2 & 15;
        } else { bx = blockIdx.x; bl = blockIdx.y; }
    }
    const int tid  = threadIdx.x;
    const int wave = tid >> 6;
    const int lane = tid & 63;
    const int l16  = lane & 15;
    const int quad = lane >> 4;

    const int pr  = bx;                              // strip pair 0..15
    const int h   = wave;                            // k-phase (j mod 4)
    const int qA  = pr * 16;                         // near strip rows
    const int qB  = (31 - pr) * 16;                  // far strip rows
    const int jdA = pr >> 2;                         // diag tile, strip A
    const int jdB = (31 - pr) >> 2;                  // diag tile, strip B

    __shared__ __align__(16) _Float16 pbuf[4][16][72];
    __shared__ __align__(16) floatx4  mbuf[3][10][64];   // merge buffer

    const _Float16* Qb = Qw  + (size_t)bl * TSEQ * HD;
    const _Float16* Kb = Kw  + (size_t)bl * TSEQ * HD;
    const _Float16* Vb = Vtw + (size_t)bl * HD * TSEQ;   // [d][t]

    half8 aQA0 = *(const half8*)(Qb + (size_t)(qA + l16) * HD + quad * 8);
    half8 aQA1 = *(const half8*)(Qb + (size_t)(qA + l16) * HD + 32 + quad * 8);
    half8 aQB0 = *(const half8*)(Qb + (size_t)(qB + l16) * HD + quad * 8);
    half8 aQB1 = *(const half8*)(Qb + (size_t)(qB + l16) * HD + 32 + quad * 8);

    half8 ones;
#pragma unroll
    for (int jj = 0; jj < 8; ++jj) ones[jj] = (_Float16)1.f;

    floatx4 accO[8], accL[2];
#pragma unroll
    for (int i = 0; i < 8; ++i)
#pragma unroll
        for (int r = 0; r < 4; ++r) accO[i][r] = 0.f;
#pragma unroll
    for (int s = 0; s < 2; ++s)
#pragma unroll
        for (int r = 0; r < 4; ++r) accL[s][r] = 0.f;

    for (int j = h; j <= jdB; j += 4) {
        const int kb = j * 64;
        const bool actA = (j <= jdA);

        // ---- K fragments (shared by both strips; dead before V loads) ----
        half8 bK0[4], bK1[4];
#pragma unroll
        for (int s4 = 0; s4 < 4; ++s4) {
            const _Float16* kp = Kb + (size_t)(kb + s4 * 16 + l16) * HD + quad * 8;
            bK0[s4] = *(const half8*)(kp);
            bK1[s4] = *(const half8*)(kp + 32);
        }

        // ---- strip A: QK^T + exp -> pbuf (st4A dies before B's QK) ----
        if (actA) {
            floatx4 st4[4];
            __builtin_amdgcn_s_setprio(1);
#pragma unroll
            for (int s4 = 0; s4 < 4; ++s4) {
#pragma unroll
                for (int r = 0; r < 4; ++r) st4[s4][r] = 0.f;
                st4[s4] = __builtin_amdgcn_mfma_f32_16x16x32_f16(bK0[s4], aQA0, st4[s4], 0, 0, 0);
                st4[s4] = __builtin_amdgcn_mfma_f32_16x16x32_f16(bK1[s4], aQA1, st4[s4], 0, 0, 0);
            }
            __builtin_amdgcn_s_setprio(0);
            const int qrow = qA + l16;
#pragma unroll
            for (int s4 = 0; s4 < 4; ++s4) {
                half4 w;
#pragma unroll
                for (int r = 0; r < 4; ++r) {
                    float p = __expf(fminf(st4[s4][r], 18.f) - MBIAS);
                    if (j == jdA) {
                        const int kcol = kb + s4 * 16 + quad * 4 + r;
                        if (kcol > qrow) p = 0.f;
                    }
                    w[r] = (_Float16)p;
                }
                *(half4*)(&pbuf[wave][l16][s4 * 16 + quad * 4]) = w;
            }
        }

        // ---- strip B: QK^T (K dies here) ----
        floatx4 stB[4];
        __builtin_amdgcn_s_setprio(1);
#pragma unroll
        for (int s4 = 0; s4 < 4; ++s4) {
#pragma unroll
            for (int r = 0; r < 4; ++r) stB[s4][r] = 0.f;
            stB[s4] = __builtin_amdgcn_mfma_f32_16x16x32_f16(bK0[s4], aQB0, stB[s4], 0, 0, 0);
            stB[s4] = __builtin_amdgcn_mfma_f32_16x16x32_f16(bK1[s4], aQB1, stB[s4], 0, 0, 0);
        }
        __builtin_amdgcn_s_setprio(0);

        // ---- V fragments (allocator reuses K's registers) ----
        half8 bV0[4], bV1[4];
#pragma unroll
        for (int s4 = 0; s4 < 4; ++s4) {
            const _Float16* vp = Vb + (size_t)(s4 * 16 + l16) * TSEQ + kb + quad * 8;
            bV0[s4] = *(const half8*)(vp);
            bV1[s4] = *(const half8*)(vp + 32);
        }

        // ---- strip A: PV (pbuf read precedes B's pbuf overwrite) ----
        if (actA) {
            half8 aP0 = *(const half8*)(&pbuf[wave][l16][quad * 8]);
            half8 aP1 = *(const half8*)(&pbuf[wave][l16][32 + quad * 8]);
            __builtin_amdgcn_s_setprio(1);
#pragma unroll
            for (int s4 = 0; s4 < 4; ++s4) {
                accO[s4] = __builtin_amdgcn_mfma_f32_16x16x32_f16(aP0, bV0[s4], accO[s4], 0, 0, 0);
                accO[s4] = __builtin_amdgcn_mfma_f32_16x16x32_f16(aP1, bV1[s4], accO[s4], 0, 0, 0);
            }
            accL[0] = __builtin_amdgcn_mfma_f32_16x16x32_f16(aP0, ones, accL[0], 0, 0, 0);
            accL[0] = __builtin_amdgcn_mfma_f32_16x16x32_f16(aP1, ones, accL[0], 0, 0, 0);
            __builtin_amdgcn_s_setprio(0);
        }

        // ---- strip B: exp -> pbuf, PV ----
        {
            const int qrow = qB + l16;
#pragma unroll
            for (int s4 = 0; s4 < 4; ++s4) {
                half4 w;
#pragma unroll
                for (int r = 0; r < 4; ++r) {
                    float p = __expf(fminf(stB[s4][r], 18.f) - MBIAS);
                    if (j == jdB) {
                        const int kcol = kb + s4 * 16 + quad * 4 + r;
                        if (kcol > qrow) p = 0.f;
                    }
                    w[r] = (_Float16)p;
                }
                *(half4*)(&pbuf[wave][l16][s4 * 16 + quad * 4]) = w;
            }
            half8 aP0 = *(const half8*)(&pbuf[wave][l16][quad * 8]);
            half8 aP1 = *(const half8*)(&pbuf[wave][l16][32 + quad * 8]);
            __builtin_amdgcn_s_setprio(1);
#pragma unroll
            for (int s4 = 0; s4 < 4; ++s4) {
                accO[4 + s4] = __builtin_amdgcn_mfma_f32_16x16x32_f16(aP0, bV0[s4], accO[4 + s4], 0, 0, 0);
                accO[4 + s4] = __builtin_amdgcn_mfma_f32_16x16x32_f16(aP1, bV1[s4], accO[4 + s4], 0, 0, 0);
            }
            accL[1] = __builtin_amdgcn_mfma_f32_16x16x32_f16(aP0, ones, accL[1], 0, 0, 0);
            accL[1] = __builtin_amdgcn_mfma_f32_16x16x32_f16(aP1, ones, accL[1], 0, 0, 0);
            __builtin_amdgcn_s_setprio(0);
        }
    }

    // ---- merge the 4 k-phases (exact: fixed-bias softmax) ----
    if (h != 0) {
#pragma unroll
        for (int i = 0; i < 8; ++i) mbuf[h - 1][i][lane] = accO[i];
        mbuf[h - 1][8][lane] = accL[0];
        mbuf[h - 1][9][lane] = accL[1];
    }
    __syncthreads();
    if (h != 0) return;

#pragma unroll
    for (int m = 0; m < 3; ++m) {
#pragma unroll
        for (int i = 0; i < 8; ++i) {
            floatx4 t = mbuf[m][i][lane];
#pragma unroll
            for (int r = 0; r < 4; ++r) accO[i][r] += t[r];
        }
        floatx4 t8 = mbuf[m][8][lane];
        floatx4 t9 = mbuf[m][9][lane];
#pragma unroll
        for (int r = 0; r < 4; ++r) { accL[0][r] += t8[r]; accL[1][r] += t9[r]; }
    }

    // ---- epilogue (phase-0 wave writes both strips) ----
#pragma unroll
    for (int s = 0; s < 2; ++s) {
        const int qbase = (s == 0) ? qA : qB;
        float inv[4];
#pragma unroll
        for (int r = 0; r < 4; ++r) inv[r] = 1.f / accL[s][r];
#pragma unroll
        for (int s4 = 0; s4 < 4; ++s4) {
            const int dcol = s4 * 16 + l16;
#pragma unroll
            for (int r = 0; r < 4; ++r) {
                const int qr = qbase + quad * 4 + r;
                out[((size_t)(b0 + bl) * TSEQ + qr) * HD + dcol] =
                    accO[s * 4 + s4][r] * inv[r];
            }
        }
    }
}

// ---------------------------------------------------------------------------
extern "C" void kernel_launch(void* const* d_in, const int* in_sizes, int n_in,
                              void* d_out, int out_size, void* d_ws, size_t ws_size,
                              hipStream_t stream)
{
    char* ws = (char*)d_ws;
    _Float16* Wp = (_Float16*)ws;                           // 147456 B
    char* qkv_base = ws + 147456;

    const size_t per_b = (size_t)3 * TSEQ * HD * sizeof(_Float16);  // 196608 B
    size_t avail = (ws_size > (size_t)147456) ? ws_size - 147456 : per_b;
    int nbc = (int)(avail / per_b);
    if (nbc > NB) nbc = NB;
    if (nbc < 1)  nbc = 1;

    const size_t chunk_elems = (size_t)nbc * TSEQ * HD;
    _Float16* Qw  = (_Float16*)qkv_base;
    _Float16* Kw  = Qw + chunk_elems;
    _Float16* Vtw = Kw + chunk_elems;

    prep_w<<<dim3((3 * CDIM * HD + 255) / 256), dim3(256), 0, stream>>>(
        (const float*)d_in[1], (const float*)d_in[3], (const float*)d_in[5], Wp);

    for (int b0 = 0; b0 < NB; b0 += nbc) {
        const int nb = (NB - b0 < nbc) ? (NB - b0) : nbc;
        qkv_gemm<<<dim3(nb * 8), dim3(256), 0, stream>>>(
            (const float*)d_in[0], Wp, (const float*)d_in[2], (const float*)d_in[4],
            (const float*)d_in[6], Qw, Kw, Vtw, b0);
        attn_kernel<<<dim3(16, nb), dim3(256), 0, stream>>>(
            Qw, Kw, Vtw, (float*)d_out, b0);
    }
}